// Round 3
// 343.375 us; speedup vs baseline: 1.0659x; 1.0659x over previous
//
#include <hip/hip_runtime.h>
#include <stdint.h>

// Problem constants
#define S2048 2048
#define DMODEL 256
#define NH 4
#define DK 64
// tokens total = 8*2048 = 16384

typedef __bf16 bf16x8 __attribute__((ext_vector_type(8)));
typedef float f32x4 __attribute__((ext_vector_type(4)));

#define MFMA16(a, b, c) __builtin_amdgcn_mfma_f32_16x16x32_bf16((a), (b), (c), 0, 0, 0)

__device__ __forceinline__ uint16_t f2bf(float f) {
  uint32_t u = __builtin_bit_cast(uint32_t, f);
  u = (u + 0x7fff + ((u >> 16) & 1)) >> 16;  // RNE; inputs are finite
  return (uint16_t)u;
}

__device__ __forceinline__ void async16(const void* g, void* l) {
  __builtin_amdgcn_global_load_lds(
      (const __attribute__((address_space(1))) unsigned int*)g,
      (__attribute__((address_space(3))) unsigned int*)l, 16, 0, 0);
}

// Stage `rows` x 64 bf16 (128B/row) from global into LDS, 16B chunks,
// chunk-XOR-swizzled (swizzle applied on SOURCE, LDS stays linear).
// 256 threads; rows must be a multiple of 32.
__device__ __forceinline__ void stage64(const char* gbase, int rstride,
                                        char* lds, int tid, int rows) {
  int iters = rows >> 5;
#pragma unroll
  for (int it = 0; it < iters; ++it) {
    int cid = (it << 8) + tid;
    int m = cid >> 3, cp = cid & 7, c = cp ^ (m & 7);
    async16(gbase + (size_t)m * rstride + (c << 4),
            lds + ((size_t)((it << 8) + (tid & ~63)) << 4));
  }
}

// Read one 16B MFMA fragment (A or B^T operand) from a swizzled 64-col tile.
// chunk = ks*4 + (lane>>4); row = rowbase + (lane&15)
__device__ __forceinline__ bf16x8 frag_ld(const char* t, int rowbase, int chunk, int l15) {
  int m = rowbase + l15;
  return *(const bf16x8*)(t + (((m << 3) + (chunk ^ (m & 7))) << 4));
}

// Same for a 32-col (64B-row) tile: 4 chunks/row, 2-bit XOR swizzle.
__device__ __forceinline__ bf16x8 frag_ld32(const char* t, int rowbase, int chunk, int l15) {
  int m = rowbase + l15;
  return *(const bf16x8*)(t + (((m << 2) + (chunk ^ (m & 3))) << 4));
}

// ---------------- cast fp32 -> bf16 for query/key/value ----------------
__global__ __launch_bounds__(256) void cast_x(const float* __restrict__ q,
                                              const float* __restrict__ k,
                                              const float* __restrict__ v,
                                              uint16_t* __restrict__ xq,
                                              uint16_t* __restrict__ xk,
                                              uint16_t* __restrict__ xv) {
  const float* src = blockIdx.y == 0 ? q : (blockIdx.y == 1 ? k : v);
  uint16_t* dst = blockIdx.y == 0 ? xq : (blockIdx.y == 1 ? xk : xv);
  size_t i = ((size_t)blockIdx.x * 256 + threadIdx.x) * 8;
  float4 a = *(const float4*)(src + i);
  float4 b = *(const float4*)(src + i + 4);
  union { uint16_t s[8]; uint4 u; } r;
  r.s[0] = f2bf(a.x); r.s[1] = f2bf(a.y); r.s[2] = f2bf(a.z); r.s[3] = f2bf(a.w);
  r.s[4] = f2bf(b.x); r.s[5] = f2bf(b.y); r.s[6] = f2bf(b.z); r.s[7] = f2bf(b.w);
  *(uint4*)(dst + i) = r.u;
}

// ---------------- cast + transpose weights (256x256): Wt[n][k] = W[k][n] ----
__global__ __launch_bounds__(256) void cast_w(const float* __restrict__ Wq,
                                              const float* __restrict__ Wk,
                                              const float* __restrict__ Wv,
                                              const float* __restrict__ Wo,
                                              uint16_t* __restrict__ Wqt,
                                              uint16_t* __restrict__ Wkt,
                                              uint16_t* __restrict__ Wvt,
                                              uint16_t* __restrict__ Wot) {
  const float* W = blockIdx.y == 0 ? Wq : blockIdx.y == 1 ? Wk : blockIdx.y == 2 ? Wv : Wo;
  uint16_t* Wt = blockIdx.y == 0 ? Wqt : blockIdx.y == 1 ? Wkt : blockIdx.y == 2 ? Wvt : Wot;
  __shared__ uint16_t t[64 * 66];  // pitch 66 -> conflict-free column reads
  int tile = blockIdx.x, tr = tile >> 2, tc = tile & 3;
  int tid = threadIdx.x;
#pragma unroll
  for (int i = 0; i < 16; ++i) {
    int e = i * 256 + tid, r = e >> 6, cl = e & 63;
    t[r * 66 + cl] = f2bf(W[(size_t)(tr * 64 + r) * 256 + tc * 64 + cl]);
  }
  __syncthreads();
#pragma unroll
  for (int i = 0; i < 16; ++i) {
    int e = i * 256 + tid, n = e >> 6, kk = e & 63;
    Wt[(size_t)(tc * 64 + n) * 256 + tr * 64 + kk] = t[kk * 66 + n];
  }
}

// ---------------- generic bt-GEMM: C[M,N] = A(MxK) * Bt(NxK)^T (+bias) ------
// tile 128x128, BK=64, 256 threads (2x2 waves of 64x64). grid=(M/128, N/128)
// OUTF32: 0 -> bf16 out, 1 -> fp32 out. BIAS: 0 none, 1 col bias[n], 2 row bias[m]
template <int OUTF32, int BIAS>
__global__ __launch_bounds__(256) void gemm_bt(const uint16_t* __restrict__ A,
                                               const uint16_t* __restrict__ Bt,
                                               const float* __restrict__ bias,
                                               void* __restrict__ Cv, int K, int ldc) {
  __shared__ char lds[32768];
  char* At = lds;
  char* Btl = lds + 16384;
  int tid = threadIdx.x, lane = tid & 63, wid = tid >> 6;
  int l15 = lane & 15, q = lane >> 4;
  int mt = blockIdx.x, nt = blockIdx.y;
  int wm = (wid >> 1) * 64, wn = (wid & 1) * 64;
  f32x4 acc[4][4] = {};
  const char* Ag = (const char*)(A + (size_t)(mt * 128) * K);
  const char* Bg = (const char*)(Bt + (size_t)(nt * 128) * K);
  int nk = K >> 6;
  for (int kt = 0; kt < nk; ++kt) {
    stage64(Ag + kt * 128, K * 2, At, tid, 128);
    stage64(Bg + kt * 128, K * 2, Btl, tid, 128);
    __syncthreads();
#pragma unroll
    for (int ks = 0; ks < 2; ++ks) {
      bf16x8 a[4], b[4];
#pragma unroll
      for (int i = 0; i < 4; ++i) a[i] = frag_ld(At, wm + i * 16, ks * 4 + q, l15);
#pragma unroll
      for (int j = 0; j < 4; ++j) b[j] = frag_ld(Btl, wn + j * 16, ks * 4 + q, l15);
#pragma unroll
      for (int i = 0; i < 4; ++i)
#pragma unroll
        for (int j = 0; j < 4; ++j) acc[i][j] = MFMA16(a[i], b[j], acc[i][j]);
    }
    __syncthreads();
  }
#pragma unroll
  for (int i = 0; i < 4; ++i) {
    int r0 = mt * 128 + wm + i * 16 + q * 4;
#pragma unroll
    for (int j = 0; j < 4; ++j) {
      int c = nt * 128 + wn + j * 16 + l15;
#pragma unroll
      for (int e = 0; e < 4; ++e) {
        float v = acc[i][j][e];
        if (BIAS == 1) v += bias[c];
        if (BIAS == 2) v += bias[r0 + e];
        size_t off = (size_t)(r0 + e) * ldc + c;
        if (OUTF32) ((float*)Cv)[off] = v;
        else ((uint16_t*)Cv)[off] = f2bf(v);
      }
    }
  }
}

// ---------------- pass 1: linv4[b,h,q] = 0.25 / sum_k exp(q.k/8) ------------
// grid = (S/128, H, B); 256 threads; wave = 32 q-rows x 128 k-cols
// (round-0 verified version, byte-identical)
__global__ __launch_bounds__(256) void attn_lsum(const uint16_t* __restrict__ Qb,
                                                 const uint16_t* __restrict__ Kb,
                                                 float* __restrict__ linv4) {
  __shared__ char lds[32768];
  char* Qt = lds;
  char* Kt = lds + 16384;
  int tid = threadIdx.x, lane = tid & 63, wid = tid >> 6;
  int l15 = lane & 15, q = lane >> 4;
  int b = blockIdx.z, h = blockIdx.y, qt = blockIdx.x;
  const char* Qg = (const char*)(Qb + ((size_t)b * S2048 + qt * 128) * DMODEL + h * DK);
  const char* Kg = (const char*)(Kb + ((size_t)b * S2048) * DMODEL + h * DK);
  stage64(Qg, DMODEL * 2, Qt, tid, 128);
  float ps[2][4] = {};
  for (int kt = 0; kt < 16; ++kt) {
    stage64(Kg + (size_t)kt * 128 * (DMODEL * 2), DMODEL * 2, Kt, tid, 128);
    __syncthreads();
#pragma unroll
    for (int i = 0; i < 2; ++i) {
      bf16x8 a0 = frag_ld(Qt, wid * 32 + i * 16, q, l15);
      bf16x8 a1 = frag_ld(Qt, wid * 32 + i * 16, 4 + q, l15);
#pragma unroll
      for (int j = 0; j < 8; ++j) {
        f32x4 s = {0.f, 0.f, 0.f, 0.f};
        s = MFMA16(a0, frag_ld(Kt, j * 16, q, l15), s);
        s = MFMA16(a1, frag_ld(Kt, j * 16, 4 + q, l15), s);
#pragma unroll
        for (int e = 0; e < 4; ++e) ps[i][e] += __expf(s[e] * 0.125f);
      }
    }
    __syncthreads();
  }
#pragma unroll
  for (int i = 0; i < 2; ++i)
#pragma unroll
    for (int e = 0; e < 4; ++e) {
      float v = ps[i][e];
      v += __shfl_xor(v, 1); v += __shfl_xor(v, 2);
      v += __shfl_xor(v, 4); v += __shfl_xor(v, 8);
      if (l15 == 0) {
        int row = qt * 128 + wid * 32 + i * 16 + q * 4 + e;
        linv4[((size_t)(b * NH + h)) * S2048 + row] = 0.25f / v;
      }
    }
}

// ---------------- fused pass 2: avg_attn write + PV accumulate --------------
// Conservative fusion built ONLY from round-0-verified patterns:
//   - QK orientation = round-0 attn_avg (A = Q frag, B = K frag, stage64/frag_ld)
//   - attn written as scalar fp32 stores (round-0 pattern)
//   - P staged through LDS (32x32 bf16, swizzled scalar writes), PV uses the
//     standard frag_ld A/B path (round-0 GEMM pattern). No swapped operands,
//     no half-zero register fragments, no cross-wave reductions.
// Grid 512: b = bid&7 (XCD-local batch -> K/V L2-resident), qt = bid>>3 (64).
// 256 threads (4 waves), 32 q-rows/block, k-loop of 32-col tiles (64 iters).
// QK roles: wq = wid&1 (16 q-rows), wk = wid>>1 (16 k-cols).
// PV roles: qg = wid&1 (16 q-rows), dg = wid>>1 (128 d-cols); acc[8] f32x4.
// LDS: K 4 heads x (32x64) = 16KB | V pair-tile 256x64 = 32KB | P 2KB = 50KB.
// 2 barriers/iter: K[kt+1] staged under PV(kt); V[pair+1] staged after odd kt.
__global__ __launch_bounds__(256) void attn_fused(const uint16_t* __restrict__ Qb,
                                                  const uint16_t* __restrict__ Kb,
                                                  const uint16_t* __restrict__ VbT,
                                                  const float* __restrict__ linv4,
                                                  float* __restrict__ attn,
                                                  uint16_t* __restrict__ out1) {
  __shared__ __align__(16) char lds[51200];
  char* Kt = lds;            // 4 x 4096 B head-subtiles (32 k-rows x 64 dk)
  char* Vt = lds + 16384;    // 256 d-rows x 64 k (one kt-pair), 32 KB
  char* Pt = lds + 49152;    // 32 q x 32 k bf16, 2 KB
  int tid = threadIdx.x, lane = tid & 63, wid = tid >> 6;
  int l15 = lane & 15, hi = lane >> 4;
  int b = blockIdx.x & 7, qt = blockIdx.x >> 3;
  int qbase = qt * 32;
  int wq = wid & 1, wk = wid >> 1;  // QK roles
  int qg = wid & 1, dg = wid >> 1;  // PV roles
  const char* Qg = (const char*)(Qb + ((size_t)b * S2048 + qbase) * DMODEL);
  const char* Kg = (const char*)(Kb + (size_t)b * S2048 * DMODEL);
  const char* Vgb = (const char*)(VbT + (size_t)b * S2048);
  // ---- prologue: stage Q per head into the K region (16 KB), hoist to regs
#pragma unroll
  for (int h = 0; h < NH; ++h)
    stage64(Qg + h * 128, DMODEL * 2, Kt + h * 4096, tid, 32);
  float li[NH][4];
#pragma unroll
  for (int h = 0; h < NH; ++h)
#pragma unroll
    for (int e = 0; e < 4; ++e)
      li[h][e] = linv4[((size_t)(b * NH + h)) * S2048 + qbase + wq * 16 + hi * 4 + e];
  __syncthreads();  // Q staged
  bf16x8 qf[NH][2];
#pragma unroll
  for (int h = 0; h < NH; ++h)
#pragma unroll
    for (int ks = 0; ks < 2; ++ks)
      qf[h][ks] = frag_ld(Kt + h * 4096, wq * 16, ks * 4 + hi, l15);
  __syncthreads();  // Q reads done; K region reusable
#pragma unroll
  for (int h = 0; h < NH; ++h)  // K[0]
    stage64(Kg + h * 128, DMODEL * 2, Kt + h * 4096, tid, 32);
  stage64(Vgb, 32768, Vt, tid, 256);  // V pair 0 (k = 0..63)
  __syncthreads();  // K[0], V[0] drained
  f32x4 acc[8] = {};
  size_t arow0 = (size_t)b * S2048 + qbase + wq * 16 + hi * 4;  // +e
#pragma unroll 2
  for (int kt = 0; kt < 64; ++kt) {
    // ---- QK^T (4 heads), exp, head-average (round-0 orientation) ----
    float Pav[4] = {0.f, 0.f, 0.f, 0.f};
#pragma unroll
    for (int h = 0; h < NH; ++h) {
      f32x4 s = {0.f, 0.f, 0.f, 0.f};
      s = MFMA16(qf[h][0], frag_ld(Kt + h * 4096, wk * 16, hi, l15), s);
      s = MFMA16(qf[h][1], frag_ld(Kt + h * 4096, wk * 16, 4 + hi, l15), s);
#pragma unroll
      for (int e = 0; e < 4; ++e) Pav[e] += __expf(s[e] * 0.125f) * li[h][e];
    }
    // P -> LDS (bf16, swizzled to match frag_ld32)
#pragma unroll
    for (int e = 0; e < 4; ++e) {
      int m = wq * 16 + hi * 4 + e, kk = wk * 16 + l15;
      *(uint16_t*)(Pt + (((m << 2) + ((kk >> 3) ^ (m & 3))) << 4) + ((kk & 7) << 1)) =
          f2bf(Pav[e]);
    }
    __syncthreads();  // B1: K[kt] reads done; P visible; V pair drained
    // avg_attn output (scalar fp32, round-0 pattern); drain covered by PV
    {
      int kc = kt * 32 + wk * 16 + l15;
#pragma unroll
      for (int e = 0; e < 4; ++e) attn[(arow0 + e) * S2048 + kc] = Pav[e];
    }
    if (kt + 1 < 64) {
#pragma unroll
      for (int h = 0; h < NH; ++h)
        stage64(Kg + (size_t)(kt + 1) * 32 * (DMODEL * 2) + h * 128, DMODEL * 2,
                Kt + h * 4096, tid, 32);
    }
    // ---- PV partial: P(32x32) @ V(32x256); ks = kt&1 selects pair half ----
    {
      int ks = kt & 1;
      bf16x8 pa = frag_ld32(Pt, qg * 16, hi, l15);
#pragma unroll
      for (int j = 0; j < 8; ++j) {
        bf16x8 vb = frag_ld(Vt, dg * 128 + j * 16, ks * 4 + hi, l15);
        acc[j] = MFMA16(pa, vb, acc[j]);
      }
    }
    __syncthreads();  // B2: Pt/Vt reads done; drains K[kt+1]
    if ((kt & 1) && kt + 1 < 64)  // stage next V pair (k = (kt+1)*32 ..)
      stage64(Vgb + (size_t)((kt + 1) >> 1) * 128, 32768, Vt, tid, 256);
  }
  // ---- epilogue: out1[qbase + qg*16 + hi*4 + e][dg*128 + j*16 + l15] ----
#pragma unroll
  for (int j = 0; j < 8; ++j) {
    size_t r0 = (size_t)b * S2048 + qbase + qg * 16 + hi * 4;
    int c = dg * 128 + j * 16 + l15;
#pragma unroll
    for (int e = 0; e < 4; ++e) out1[(r0 + e) * DMODEL + c] = f2bf(acc[j][e]);
  }
}

extern "C" void kernel_launch(void* const* d_in, const int* in_sizes, int n_in,
                              void* d_out, int out_size, void* d_ws, size_t ws_size,
                              hipStream_t stream) {
  const float* query = (const float*)d_in[0];
  const float* key_i = (const float*)d_in[1];
  const float* value = (const float*)d_in[2];
  const float* W_q = (const float*)d_in[3];
  const float* b_q = (const float*)d_in[4];
  const float* W_k = (const float*)d_in[5];
  const float* b_k = (const float*)d_in[6];
  const float* W_v = (const float*)d_in[7];
  const float* b_v = (const float*)d_in[8];
  const float* W_o = (const float*)d_in[9];
  const float* b_o = (const float*)d_in[10];

  char* ws = (char*)d_ws;
  const size_t SZX = 16384ull * 256 * 2;  // one bf16 token matrix = 8 MB
  uint16_t* Xq = (uint16_t*)(ws + 0 * SZX);
  uint16_t* Xk = (uint16_t*)(ws + 1 * SZX);
  uint16_t* Xv = (uint16_t*)(ws + 2 * SZX);
  uint16_t* Qb = (uint16_t*)(ws + 3 * SZX);
  uint16_t* Kb = (uint16_t*)(ws + 4 * SZX);
  uint16_t* VbT = (uint16_t*)(ws + 5 * SZX);   // (256 x 16384) = V^T
  uint16_t* out1b = (uint16_t*)(ws + 6 * SZX);
  uint16_t* Wqt = (uint16_t*)(ws + 7 * SZX);
  uint16_t* Wkt = (uint16_t*)(ws + 7 * SZX + 131072);
  uint16_t* Wvt = (uint16_t*)(ws + 7 * SZX + 2 * 131072);
  uint16_t* Wot = (uint16_t*)(ws + 7 * SZX + 3 * 131072);
  float* linv4 = (float*)(ws + 7 * SZX + 4 * 131072);

  float* out = (float*)d_out;
  float* attn = out + 16384ull * 256;  // avg_attn region of d_out

  cast_x<<<dim3(2048, 3), 256, 0, stream>>>(query, key_i, value, Xq, Xk, Xv);
  cast_w<<<dim3(16, 4), 256, 0, stream>>>(W_q, W_k, W_v, W_o, Wqt, Wkt, Wvt, Wot);
  // Q = Xq @ Wq + bq  (col bias)
  gemm_bt<0, 1><<<dim3(128, 2), 256, 0, stream>>>(Xq, Wqt, b_q, Qb, 256, 256);
  gemm_bt<0, 1><<<dim3(128, 2), 256, 0, stream>>>(Xk, Wkt, b_k, Kb, 256, 256);
  // VbT[d][s] = sum_k Wvt[d][k] * Xv[s][k] + bv[d]  (row bias) -> V^T directly
  gemm_bt<0, 2><<<dim3(2, 128), 256, 0, stream>>>(Wvt, Xv, b_v, VbT, 256, 16384);
  attn_lsum<<<dim3(16, 4, 8), 256, 0, stream>>>(Qb, Kb, linv4);
  attn_fused<<<dim3(512), 256, 0, stream>>>(Qb, Kb, VbT, linv4, attn, out1b);
  gemm_bt<1, 1><<<dim3(128, 2), 256, 0, stream>>>(out1b, Wot, b_o, out, 256, 256);
}